// Round 4
// baseline (1051.300 us; speedup 1.0000x reference)
//
#include <hip/hip_runtime.h>

namespace {

constexpr int B_  = 2;
constexpr int N_  = 512;
constexpr int IN_ = 512;
constexpr int M_  = 300;   // MEM
constexpr int H_  = 64;    // HID
constexpr float SLOPE_ = 0.01f;
constexpr int NB_ = 512;   // persistent grid: 2 blocks/CU on 256 CUs (guaranteed
                           // co-resident: 17.5KB LDS/block, VGPR << 256)

// ---- workspace layout (float offsets) ----
constexpr long OFF_BAR = 0;                         // [0]=count, [1]=gen
constexpr long OFF_H0  = 64;
constexpr long OFF_SI0 = OFF_H0  + 1024L * 300;     // h0: 1024x300
constexpr long OFF_SJ0 = OFF_SI0 + 1024L * 64;
constexpr long OFF_Z   = OFF_SJ0 + 1024L * 64;      // Z[0..1]=layer0, Z[2..3]=layer1
constexpr long OFF_H1  = OFF_Z   + 64;
constexpr long OFF_F1P = OFF_H1  + 1024L * 300;     // unnormalized p0@h0
constexpr long ZERO_END= OFF_F1P + 1024L * 300;     // ---- end of zeroed region ----
constexpr long OFF_P0  = ZERO_END;                  // 2x512x512 (fully written)
constexpr long OFF_P1  = OFF_P0  + 2L * 512 * 512;  // total ~8.4 MB << ws_size

// LDS: gemm uses 8448 B, attn uses 17408 B + reduce scratch
constexpr int SMEM_BYTES = 17472;

// ---------------------------------------------------------------------------
// Grid-wide barrier (all NB_ blocks co-resident by occupancy construction).
// Release fence -> arrive on count -> last block resets count, bumps gen ->
// spinners acquire gen. Device ("agent") scope throughout.
// ---------------------------------------------------------------------------
__device__ __forceinline__ void gsync(unsigned* bar)
{
    __syncthreads();
    if (threadIdx.x == 0) {
        __threadfence();  // release prior global writes to device scope
        unsigned g = __hip_atomic_load(&bar[1], __ATOMIC_RELAXED, __HIP_MEMORY_SCOPE_AGENT);
        unsigned a = __hip_atomic_fetch_add(&bar[0], 1u, __ATOMIC_ACQ_REL, __HIP_MEMORY_SCOPE_AGENT);
        if (a == (unsigned)(gridDim.x - 1)) {
            __hip_atomic_store(&bar[0], 0u, __ATOMIC_RELAXED, __HIP_MEMORY_SCOPE_AGENT);
            __hip_atomic_fetch_add(&bar[1], 1u, __ATOMIC_RELEASE, __HIP_MEMORY_SCOPE_AGENT);
        } else {
            while (__hip_atomic_load(&bar[1], __ATOMIC_ACQUIRE, __HIP_MEMORY_SCOPE_AGENT) == g)
                __builtin_amdgcn_s_sleep(2);
        }
        __threadfence();
    }
    __syncthreads();
}

// ---------------------------------------------------------------------------
// One 64x64 output tile, K-range [kstart,kend), 4x4 micro-tile, TK=16.
// C[r,c] += scale*acc + bias[c]   via atomicAdd (C pre-zeroed).
// kstart/kend multiples of 4; Cc multiple of 4; lda rows 16B-aligned.
// ---------------------------------------------------------------------------
__device__ __forceinline__ void gemm_unit(
    const float* __restrict__ A, const float* __restrict__ W,
    const float* __restrict__ bias, float scale, float* __restrict__ C,
    int lda, int ldw, int ldc, int Cc,
    int row0, int col0, int kstart, int kend, char* smem)
{
    float* As = (float*)smem;                 // [16][68]  (stride 68: <=2-way, free)
    float* Ws = (float*)(smem + 16 * 68 * 4); // [16][64]

    const int t   = threadIdx.x;
    const int tm0 = (t >> 4) * 4;
    const int tn0 = (t & 15) * 4;
    const int arow = row0 + (t >> 2);
    const int akg  = (t & 3) * 4;
    const int wk   = t >> 4;
    const int wc   = (t & 15) * 4;

    float acc[4][4] = {};

    for (int k0 = kstart; k0 < kend; k0 += 16) {
        float4 av;
        if (k0 + akg + 4 <= kend) {
            av = *(const float4*)(A + (long)arow * lda + k0 + akg);
        } else {
            float tv[4];
            #pragma unroll
            for (int u = 0; u < 4; ++u) {
                const int k = k0 + akg + u;
                tv[u] = (k < kend) ? A[(long)arow * lda + k] : 0.0f;
            }
            av = make_float4(tv[0], tv[1], tv[2], tv[3]);
        }
        As[(akg + 0) * 68 + (t >> 2)] = av.x;
        As[(akg + 1) * 68 + (t >> 2)] = av.y;
        As[(akg + 2) * 68 + (t >> 2)] = av.z;
        As[(akg + 3) * 68 + (t >> 2)] = av.w;

        {
            const int gk = k0 + wk;
            float4 wv = make_float4(0.f, 0.f, 0.f, 0.f);
            if (gk < kend && col0 + wc + 3 < Cc)
                wv = *(const float4*)(W + (long)gk * ldw + col0 + wc);
            *(float4*)&Ws[wk * 64 + wc] = wv;
        }
        __syncthreads();

        #pragma unroll
        for (int k = 0; k < 16; ++k) {
            const float4 a4 = *(const float4*)&As[k * 68 + tm0];
            const float4 w4 = *(const float4*)&Ws[k * 64 + tn0];
            const float aa[4] = {a4.x, a4.y, a4.z, a4.w};
            const float ww[4] = {w4.x, w4.y, w4.z, w4.w};
            #pragma unroll
            for (int i = 0; i < 4; ++i)
                #pragma unroll
                for (int j = 0; j < 4; ++j)
                    acc[i][j] = fmaf(aa[i], ww[j], acc[i][j]);
        }
        __syncthreads();
    }

    const int cbase = col0 + tn0;
    float bv[4] = {0.f, 0.f, 0.f, 0.f};
    if (bias != nullptr) {
        #pragma unroll
        for (int j = 0; j < 4; ++j)
            if (cbase + j < Cc) bv[j] = bias[cbase + j];
    }
    #pragma unroll
    for (int i = 0; i < 4; ++i) {
        const int r = row0 + tm0 + i;
        #pragma unroll
        for (int j = 0; j < 4; ++j)
            if (cbase + j < Cc)
                atomicAdd(&C[(long)r * ldc + cbase + j], fmaf(acc[i][j], scale, bv[j]));
    }
}

// ---------------------------------------------------------------------------
// Attention tile (32i x 32j): e=leaky_relu(sum_h relu(si+sj)*a2w + a2b),
// p=adj*exp(e), Z += sum(p). Max-subtraction skipped: |e|<=O(10), fp32-exact,
// and softmax(l)==exp(l)/sum identically. Softmax is over flat N*N per batch.
// ---------------------------------------------------------------------------
__device__ __forceinline__ void attn_unit(
    const float* __restrict__ si, const float* __restrict__ sj,
    const float* __restrict__ adjb, const float* __restrict__ a2w,
    float a2bv, float* __restrict__ pb, float* __restrict__ Zp,
    int i0, int j0, char* smem)
{
    float* Si  = (float*)smem;                  // [32][68]
    float* Sj  = (float*)(smem + 32 * 68 * 4);  // [32][68]
    float* red = (float*)(smem + 2 * 32 * 68 * 4);

    const int t = threadIdx.x;
    {
        const int r  = t >> 3;
        const int hc = (t & 7) * 8;
        const float* gi = si + (long)(i0 + r) * H_ + hc;
        const float* gj = sj + (long)(j0 + r) * H_ + hc;
        *(float4*)&Si[r * 68 + hc]     = *(const float4*)(gi);
        *(float4*)&Si[r * 68 + hc + 4] = *(const float4*)(gi + 4);
        *(float4*)&Sj[r * 68 + hc]     = *(const float4*)(gj);
        *(float4*)&Sj[r * 68 + hc + 4] = *(const float4*)(gj + 4);
    }
    __syncthreads();

    const int i  = t >> 3;
    const int jl = t & 7;

    float e[4] = {0.f, 0.f, 0.f, 0.f};
    #pragma unroll
    for (int h0 = 0; h0 < H_; h0 += 4) {
        const float4 a4 = *(const float4*)&Si[i * 68 + h0];
        const float w0v = a2w[h0 + 0];
        const float w1v = a2w[h0 + 1];
        const float w2v = a2w[h0 + 2];
        const float w3v = a2w[h0 + 3];
        #pragma unroll
        for (int u = 0; u < 4; ++u) {
            const float4 b4 = *(const float4*)&Sj[(jl + 8 * u) * 68 + h0];
            e[u] = fmaf(fmaxf(a4.x + b4.x, 0.f), w0v, e[u]);
            e[u] = fmaf(fmaxf(a4.y + b4.y, 0.f), w1v, e[u]);
            e[u] = fmaf(fmaxf(a4.z + b4.z, 0.f), w2v, e[u]);
            e[u] = fmaf(fmaxf(a4.w + b4.w, 0.f), w3v, e[u]);
        }
    }

    const long rowbase = (long)(i0 + i) * N_ + j0 + jl;
    float lsum = 0.f;
    #pragma unroll
    for (int u = 0; u < 4; ++u) {
        float ev = e[u] + a2bv;
        ev = (ev >= 0.f) ? ev : SLOPE_ * ev;
        const float m  = adjb[rowbase + 8 * u];
        const float pv = m * __expf(ev);
        pb[rowbase + 8 * u] = pv;
        lsum += pv;
    }

    #pragma unroll
    for (int off = 32; off > 0; off >>= 1)
        lsum += __shfl_down(lsum, off, 64);
    if ((t & 63) == 0) red[t >> 6] = lsum;
    __syncthreads();
    if (t == 0)
        atomicAdd(Zp, red[0] + red[1] + red[2] + red[3]);
    __syncthreads();   // protect red[] before next unit reuses smem
}

// ---------------------------------------------------------------------------
// The whole 2-layer GAT in one persistent kernel, 8 grid barriers.
// ---------------------------------------------------------------------------
__global__ __launch_bounds__(256)
void gat_mega(const float* __restrict__ feature, const float* __restrict__ adj,
              const float* __restrict__ w0, const float* __restrict__ b0,
              const float* __restrict__ w1, const float* __restrict__ b1,
              const float* __restrict__ a1w, const float* __restrict__ a1b,
              const float* __restrict__ a2w, const float* __restrict__ a2b,
              float* __restrict__ out, float* __restrict__ ws)
{
    __shared__ __align__(16) char smem[SMEM_BYTES];
    unsigned* bar = (unsigned*)(ws + OFF_BAR);
    float* h0  = ws + OFF_H0;
    float* si0 = ws + OFF_SI0;
    float* sj0 = ws + OFF_SJ0;
    float* Zs  = ws + OFF_Z;
    float* h1  = ws + OFF_H1;
    float* f1p = ws + OFF_F1P;
    float* p0  = ws + OFF_P0;
    float* p1  = ws + OFF_P1;
    const float a2bv = a2b[0];
    const int blk = blockIdx.x;

    // P1: h0 = feature @ w0 + b0   (1024x512 @ 512x300), 80 tiles x 4 chunks
    for (int u = blk; u < 320; u += NB_) {
        const int ct = u % 5, rt = (u / 5) % 16, ch = u / 80;
        gemm_unit(feature, w0, ch == 0 ? b0 : nullptr, 1.0f, h0,
                  IN_, M_, M_, M_, rt * 64, ct * 64, ch * 128, min(ch * 128 + 128, IN_), smem);
    }
    gsync(bar);

    // P2: si0|sj0 = h0 @ a1w_top|bot (+a1b on sj)  16 tiles x 2 x 5 chunks
    for (int u = blk; u < 160; u += NB_) {
        const int half = u & 1, rt = (u >> 1) % 16, ch = u / 32;
        gemm_unit(h0, a1w + (long)half * M_ * H_,
                  (ch == 0 && half == 1) ? a1b : nullptr, 1.0f,
                  half ? sj0 : si0, M_, H_, H_, H_,
                  rt * 64, 0, ch * 60, min(ch * 60 + 60, M_), smem);
    }
    gsync(bar);

    // P3: p0, Z0   512 tiles
    for (int u = blk; u < 512; u += NB_) {
        const int b = u >> 8, r = u & 255;
        attn_unit(si0 + (long)b * N_ * H_, sj0 + (long)b * N_ * H_,
                  adj + (long)b * N_ * N_, a2w, a2bv,
                  p0 + (long)b * N_ * N_, &Zs[b], (r >> 4) * 32, (r & 15) * 32, smem);
    }
    gsync(bar);

    // P4: f1p = p0 @ h0 (unnormalized)  per-batch 512x512 @ 512x300
    for (int u = blk; u < 320; u += NB_) {
        const int b = u & 1, ct = (u >> 1) % 5, rt = (u / 10) % 8, ch = u / 80;
        gemm_unit(p0 + (long)b * N_ * N_, h0 + (long)b * N_ * M_, nullptr, 1.0f,
                  f1p + (long)b * N_ * M_, N_, M_, M_, M_,
                  rt * 64, ct * 64, ch * 128, min(ch * 128 + 128, N_), smem);
    }
    gsync(bar);

    // P5: h1 = (f1p @ w1)*(1/Z0[b]) + b1   (deferred softmax normalization)
    for (int u = blk; u < 400; u += NB_) {
        const int ct = u % 5, rt = (u / 5) % 16, ch = u / 80;
        const int row0 = rt * 64;
        const float sc = 1.0f / Zs[row0 >= 512 ? 1 : 0];
        gemm_unit(f1p, w1, ch == 0 ? b1 : nullptr, sc, h1,
                  M_, M_, M_, M_, row0, ct * 64, ch * 60, min(ch * 60 + 60, M_), smem);
    }
    gsync(bar);

    // P6a: zero the si1|sj1 arena (p0's space is dead after P4 but holds
    // stale attention values — BOTH halves must be cleared: 2*1024*64 floats).
    for (long i = blk * 256L + threadIdx.x; i < 2L * 1024 * H_; i += NB_ * 256L)
        p0[i] = 0.0f;
    gsync(bar);

    // P6b: si1|sj1 = h1 @ a1w_top|bot (+a1b on sj)
    {
        float* si1 = p0;
        float* sj1 = p0 + 1024L * H_;
        for (int u = blk; u < 160; u += NB_) {
            const int half = u & 1, rt = (u >> 1) % 16, ch = u / 32;
            gemm_unit(h1, a1w + (long)half * M_ * H_,
                      (ch == 0 && half == 1) ? a1b : nullptr, 1.0f,
                      half ? sj1 : si1, M_, H_, H_, H_,
                      rt * 64, 0, ch * 60, min(ch * 60 + 60, M_), smem);
        }
    }
    gsync(bar);

    // P7: p1, Z1
    {
        float* si1 = p0;
        float* sj1 = p0 + 1024L * H_;
        for (int u = blk; u < 512; u += NB_) {
            const int b = u >> 8, r = u & 255;
            attn_unit(si1 + (long)b * N_ * H_, sj1 + (long)b * N_ * H_,
                      adj + (long)b * N_ * N_, a2w, a2bv,
                      p1 + (long)b * N_ * N_, &Zs[2 + b], (r >> 4) * 32, (r & 15) * 32, smem);
        }
    }
    gsync(bar);

    // P8: out += p1 @ h1 (unnormalized; out pre-zeroed by host memset)
    for (int u = blk; u < 320; u += NB_) {
        const int b = u & 1, ct = (u >> 1) % 5, rt = (u / 10) % 8, ch = u / 80;
        gemm_unit(p1 + (long)b * N_ * N_, h1 + (long)b * N_ * M_, nullptr, 1.0f,
                  out + (long)b * N_ * M_, N_, M_, M_, M_,
                  rt * 64, ct * 64, ch * 128, min(ch * 128 + 128, N_), smem);
    }
    gsync(bar);

    // P9: out *= 1/Z1[b]   (76800 float4s; batch boundary at 38400 is exact)
    {
        const float z0 = 1.0f / Zs[2], z1 = 1.0f / Zs[3];
        float4* o4 = (float4*)out;
        for (int i = blk * 256 + threadIdx.x; i < 76800; i += NB_ * 256) {
            const float s = (i < 38400) ? z0 : z1;
            float4 v = o4[i];
            v.x *= s; v.y *= s; v.z *= s; v.w *= s;
            o4[i] = v;
        }
    }
}

} // namespace

extern "C" void kernel_launch(void* const* d_in, const int* in_sizes, int n_in,
                              void* d_out, int out_size, void* d_ws, size_t ws_size,
                              hipStream_t stream)
{
    const float* feature = (const float*)d_in[0];
    const float* adj     = (const float*)d_in[1];
    const float* w0      = (const float*)d_in[2];
    const float* b0      = (const float*)d_in[3];
    const float* w1      = (const float*)d_in[4];
    const float* b1      = (const float*)d_in[5];
    const float* a1w     = (const float*)d_in[6];
    const float* a1b     = (const float*)d_in[7];
    const float* a2w     = (const float*)d_in[8];
    const float* a2b     = (const float*)d_in[9];
    float* out = (float*)d_out;
    float* ws  = (float*)d_ws;

    // zero barrier state + all split-K accumulators (h0,si0,sj0,Z,h1,f1p)
    hipMemsetAsync(ws, 0, (size_t)ZERO_END * 4, stream);
    // zero out (P8 split-K target)
    hipMemsetAsync(out, 0, (size_t)B_ * N_ * M_ * 4, stream);

    gat_mega<<<dim3(NB_), dim3(256), 0, stream>>>(
        feature, adj, w0, b0, w1, b1, a1w, a1b, a2w, a2b, out, ws);
}

// Round 5
// 325.471 us; speedup vs baseline: 3.2301x; 3.2301x over previous
//
#include <hip/hip_runtime.h>

namespace {

constexpr int B_  = 2;
constexpr int N_  = 512;
constexpr int IN_ = 512;
constexpr int M_  = 300;   // MEM
constexpr int H_  = 64;    // HID
constexpr float SLOPE_ = 0.01f;

// ---- workspace layout (float offsets); one memset covers [0, ZERO_END) ----
constexpr long OFF_H0   = 0;                         // 1024 x 300
constexpr long OFF_SI0  = OFF_H0  + 1024L * 300;     // 1024 x 64
constexpr long OFF_SJ0  = OFF_SI0 + 1024L * 64;      // 1024 x 64 (contig after SI0)
constexpr long OFF_H1   = OFF_SJ0 + 1024L * 64;
constexpr long OFF_SI1  = OFF_H1  + 1024L * 300;
constexpr long OFF_SJ1  = OFF_SI1 + 1024L * 64;
constexpr long OFF_F1   = OFF_SJ1 + 1024L * 64;      // normalized att0 @ h0
constexpr long OFF_Z    = OFF_F1  + 1024L * 300;     // Z[0..1]=L0, Z[2..3]=L1
constexpr long ZERO_END = OFF_Z   + 16;
constexpr long OFF_P0   = ZERO_END;                  // 2 x 512 x 512 (fully written)
constexpr long OFF_P1   = OFF_P0  + 2L * 512 * 512;  // total ~8.9 MB

// ---------------------------------------------------------------------------
// Split-K fp32 GEMM, 64x64 tile, 256 threads, 4x4 micro-tile, TK=16,
// register double-buffered global->LDS staging (prefetch next K-slab while
// computing current one: hides the cold-L2/L3 ~600ns load latency).
//   z = sel * nchunk + chunk; sel picks batch / W-half via strides.
//   scale = Zsum ? 1/Zsum[sel] : 1  (constant per z => commutes with split-K)
//   C += scale*acc (+ bias[sel] on chunk 0)  via atomicAdd (C pre-zeroed).
// A row stride == K. W/C row stride == Cc. R multiple of 64, Cc multiple of 4.
// ---------------------------------------------------------------------------
__global__ __launch_bounds__(256)
void gemm_splitk(const float* __restrict__ Ab, const float* __restrict__ Wb,
                 const float* __restrict__ bias0, const float* __restrict__ bias1,
                 const float* __restrict__ Zsum, float* __restrict__ Cb,
                 int K, int Cc, int Kc, int nchunk,
                 long strA, long strW, long strC)
{
    __shared__ __align__(16) float As[16][68];  // [k][m]; stride 68: <=2-way (free)
    __shared__ __align__(16) float Ws[16][64];  // [k][n]

    const int sel   = blockIdx.z / nchunk;
    const int chunk = blockIdx.z % nchunk;
    const float* A = Ab + (long)sel * strA;
    const float* W = Wb + (long)sel * strW;
    float*       C = Cb + (long)sel * strC;
    const float* bias = (sel == 0) ? bias0 : bias1;

    const int kstart = chunk * Kc;
    const int kend   = min(kstart + Kc, K);

    const int t    = threadIdx.x;
    const int row0 = blockIdx.y * 64;
    const int col0 = blockIdx.x * 64;
    const int tm0  = (t >> 4) * 4;
    const int tn0  = (t & 15) * 4;

    const int arow = row0 + (t >> 2);     // 64 rows, 4 threads/row
    const int akg  = (t & 3) * 4;         // k sub-offset (0,4,8,12)
    const int wk   = t >> 4;              // 0..15
    const int wc   = (t & 15) * 4;        // 0..60

    auto loadA = [&](int k0) -> float4 {
        if (k0 + akg + 4 <= kend)
            return *(const float4*)(A + (long)arow * K + k0 + akg);
        float tv[4];
        #pragma unroll
        for (int u = 0; u < 4; ++u) {
            const int k = k0 + akg + u;
            tv[u] = (k < kend) ? A[(long)arow * K + k] : 0.0f;
        }
        return make_float4(tv[0], tv[1], tv[2], tv[3]);
    };
    auto loadW = [&](int k0) -> float4 {
        const int gk = k0 + wk;
        if (gk < kend)
            return *(const float4*)(W + (long)gk * Cc + col0 + wc);
        return make_float4(0.f, 0.f, 0.f, 0.f);
    };

    float acc[4][4] = {};
    float4 av = loadA(kstart);
    float4 wv = loadW(kstart);

    for (int k0 = kstart; k0 < kend; k0 += 16) {
        As[akg + 0][t >> 2] = av.x;
        As[akg + 1][t >> 2] = av.y;
        As[akg + 2][t >> 2] = av.z;
        As[akg + 3][t >> 2] = av.w;
        *(float4*)&Ws[wk][wc] = wv;
        __syncthreads();

        if (k0 + 16 < kend) {           // prefetch next slab behind the compute
            av = loadA(k0 + 16);
            wv = loadW(k0 + 16);
        }

        #pragma unroll
        for (int k = 0; k < 16; ++k) {
            const float4 a4 = *(const float4*)&As[k][tm0];
            const float4 w4 = *(const float4*)&Ws[k][tn0];
            const float aa[4] = {a4.x, a4.y, a4.z, a4.w};
            const float ww[4] = {w4.x, w4.y, w4.z, w4.w};
            #pragma unroll
            for (int i = 0; i < 4; ++i)
                #pragma unroll
                for (int j = 0; j < 4; ++j)
                    acc[i][j] = fmaf(aa[i], ww[j], acc[i][j]);
        }
        __syncthreads();
    }

    const float scale = (Zsum != nullptr) ? (1.0f / Zsum[sel]) : 1.0f;
    const int cbase = col0 + tn0;
    float bv[4] = {0.f, 0.f, 0.f, 0.f};
    if (bias != nullptr && chunk == 0) {
        #pragma unroll
        for (int j = 0; j < 4; ++j)
            if (cbase + j < Cc) bv[j] = bias[cbase + j];
    }
    #pragma unroll
    for (int i = 0; i < 4; ++i) {
        const int r = row0 + tm0 + i;
        #pragma unroll
        for (int j = 0; j < 4; ++j)
            if (cbase + j < Cc)
                atomicAdd(&C[(long)r * Cc + cbase + j], fmaf(acc[i][j], scale, bv[j]));
    }
}

// ---------------------------------------------------------------------------
// Attention numerator (32i x 32j tile per block):
//   e = leaky_relu( sum_h relu(si[i,h]+sj[j,h]) * a2w[h] + a2b )
//   p = adj * exp(e);  Z[b] += sum(p)    (softmax over flat N*N per batch)
// Max-subtraction skipped: |e| = O(10) so fp32 exp is exact-safe and
// softmax(l) == exp(l)/sum(exp(l)) identically.
// ---------------------------------------------------------------------------
__global__ __launch_bounds__(256)
void attn_p_kernel(const float* __restrict__ si, const float* __restrict__ sj,
                   const float* __restrict__ adj, const float* __restrict__ a2w,
                   const float* __restrict__ a2b, float* __restrict__ p,
                   float* __restrict__ Zsum)
{
    __shared__ __align__(16) float Si[32][68];
    __shared__ __align__(16) float Sj[32][68];

    const int b  = blockIdx.z;
    const int i0 = blockIdx.y * 32;
    const int j0 = blockIdx.x * 32;
    const int t  = threadIdx.x;

    {   // stage 32x64 tiles of si and sj
        const int r  = t >> 3;
        const int hc = (t & 7) * 8;
        const float* gi = si + ((long)(b * N_ + i0 + r)) * H_ + hc;
        const float* gj = sj + ((long)(b * N_ + j0 + r)) * H_ + hc;
        *(float4*)&Si[r][hc]     = *(const float4*)(gi);
        *(float4*)&Si[r][hc + 4] = *(const float4*)(gi + 4);
        *(float4*)&Sj[r][hc]     = *(const float4*)(gj);
        *(float4*)&Sj[r][hc + 4] = *(const float4*)(gj + 4);
    }
    __syncthreads();

    const int i  = t >> 3;
    const int jl = t & 7;

    float e[4] = {0.f, 0.f, 0.f, 0.f};
    #pragma unroll
    for (int h0 = 0; h0 < H_; h0 += 4) {
        const float4 a4 = *(const float4*)&Si[i][h0];
        const float w0v = a2w[h0 + 0];
        const float w1v = a2w[h0 + 1];
        const float w2v = a2w[h0 + 2];
        const float w3v = a2w[h0 + 3];
        #pragma unroll
        for (int u = 0; u < 4; ++u) {
            const float4 b4 = *(const float4*)&Sj[jl + 8 * u][h0];
            e[u] = fmaf(fmaxf(a4.x + b4.x, 0.f), w0v, e[u]);
            e[u] = fmaf(fmaxf(a4.y + b4.y, 0.f), w1v, e[u]);
            e[u] = fmaf(fmaxf(a4.z + b4.z, 0.f), w2v, e[u]);
            e[u] = fmaf(fmaxf(a4.w + b4.w, 0.f), w3v, e[u]);
        }
    }

    const float a2bv = a2b[0];
    const long rowbase = ((long)(b * N_ + i0 + i)) * N_ + j0 + jl;
    float lsum = 0.f;
    #pragma unroll
    for (int u = 0; u < 4; ++u) {
        float ev = e[u] + a2bv;
        ev = (ev >= 0.f) ? ev : SLOPE_ * ev;
        const float m  = adj[rowbase + 8 * u];
        const float pv = m * __expf(ev);
        p[rowbase + 8 * u] = pv;
        lsum += pv;
    }

    #pragma unroll
    for (int off = 32; off > 0; off >>= 1)
        lsum += __shfl_down(lsum, off, 64);
    __shared__ float red[4];
    if ((t & 63) == 0) red[t >> 6] = lsum;
    __syncthreads();
    if (t == 0)
        atomicAdd(&Zsum[b], red[0] + red[1] + red[2] + red[3]);
}

} // namespace

extern "C" void kernel_launch(void* const* d_in, const int* in_sizes, int n_in,
                              void* d_out, int out_size, void* d_ws, size_t ws_size,
                              hipStream_t stream)
{
    const float* feature = (const float*)d_in[0];
    const float* adj     = (const float*)d_in[1];
    const float* w0      = (const float*)d_in[2];
    const float* b0      = (const float*)d_in[3];
    const float* w1      = (const float*)d_in[4];
    const float* b1      = (const float*)d_in[5];
    const float* a1w     = (const float*)d_in[6];   // (600, 64) row-major
    const float* a1b     = (const float*)d_in[7];
    const float* a2w     = (const float*)d_in[8];
    const float* a2b     = (const float*)d_in[9];
    float* out = (float*)d_out;
    float* ws  = (float*)d_ws;

    float* h0  = ws + OFF_H0;
    float* si0 = ws + OFF_SI0;   // sj0 = si0 + 65536 (contiguous, sel-strided)
    float* h1  = ws + OFF_H1;
    float* si1 = ws + OFF_SI1;
    float* f1  = ws + OFF_F1;
    float* Zs  = ws + OFF_Z;
    float* p0  = ws + OFF_P0;
    float* p1  = ws + OFF_P1;

    const long NN = (long)N_ * N_;
    const long NM = (long)N_ * M_;

    // one memset zeroes every split-K accumulator + Z for both layers
    hipMemsetAsync(ws, 0, (size_t)ZERO_END * 4, stream);
    hipMemsetAsync(out, 0, (size_t)B_ * N_ * M_ * 4, stream);

    // ---- layer 0 ----
    // h0 = feature @ w0 + b0       (1024x512)@(512x300), Kc=64, nch=8
    gemm_splitk<<<dim3(5, 16, 8), dim3(256), 0, stream>>>(
        feature, w0, b0, nullptr, nullptr, h0, IN_, M_, 64, 8, 0, 0, 0);
    // [si0|sj0] = h0 @ [a1w_top|a1w_bot(+a1b)]    Kc=32, nch=10
    gemm_splitk<<<dim3(1, 16, 20), dim3(256), 0, stream>>>(
        h0, a1w, nullptr, a1b, nullptr, si0, M_, H_, 32, 10,
        0, (long)M_ * H_, (long)B_ * N_ * H_);
    attn_p_kernel<<<dim3(16, 16, B_), dim3(256), 0, stream>>>(
        si0, si0 + (long)B_ * N_ * H_, adj, a2w, a2b, p0, Zs);
    // f1 = (1/Z0[b]) * p0 @ h0     per-batch (512x512)@(512x300), Kc=64, nch=8
    gemm_splitk<<<dim3(5, 8, 16), dim3(256), 0, stream>>>(
        p0, h0, nullptr, nullptr, Zs, f1, N_, M_, 64, 8, NN, NM, NM);

    // ---- layer 1 ----
    // h1 = f1 @ w1 + b1            (1024x300)@(300x300), Kc=64, nch=5
    gemm_splitk<<<dim3(5, 16, 5), dim3(256), 0, stream>>>(
        f1, w1, b1, nullptr, nullptr, h1, M_, M_, 64, 5, 0, 0, 0);
    gemm_splitk<<<dim3(1, 16, 20), dim3(256), 0, stream>>>(
        h1, a1w, nullptr, a1b, nullptr, si1, M_, H_, 32, 10,
        0, (long)M_ * H_, (long)B_ * N_ * H_);
    attn_p_kernel<<<dim3(16, 16, B_), dim3(256), 0, stream>>>(
        si1, si1 + (long)B_ * N_ * H_, adj, a2w, a2b, p1, Zs + 2);
    // out = (1/Z1[b]) * p1 @ h1
    gemm_splitk<<<dim3(5, 8, 16), dim3(256), 0, stream>>>(
        p1, h1, nullptr, nullptr, Zs + 2, out, N_, M_, 64, 8, NN, NM, NM);
}

// Round 6
// 173.906 us; speedup vs baseline: 6.0452x; 1.8715x over previous
//
#include <hip/hip_runtime.h>

namespace {

constexpr int B_  = 2;
constexpr int N_  = 512;
constexpr int IN_ = 512;
constexpr int M_  = 300;   // MEM
constexpr int H_  = 64;    // HID
constexpr float SLOPE_ = 0.01f;

// ---- workspace layout (float offsets). No memsets: every buffer is fully
// written by a plain store before it is read. ----
constexpr long OFF_W0AI = 0;                          // 512 x 64
constexpr long OFF_W0AJ = OFF_W0AI + 512L * 64;
constexpr long OFF_W1AI = OFF_W0AJ + 512L * 64;       // 300 x 64
constexpr long OFF_W1AJ = OFF_W1AI + 300L * 64;
constexpr long OFF_BSI0 = OFF_W1AJ + 300L * 64;       // 4 x 64 bias combos
constexpr long OFF_BSJ0 = OFF_BSI0 + 64;
constexpr long OFF_BSI1 = OFF_BSJ0 + 64;
constexpr long OFF_BSJ1 = OFF_BSI1 + 64;
constexpr long OFF_H0   = OFF_BSJ1 + 64;              // 1024 x 300
constexpr long OFF_SI0  = OFF_H0   + 1024L * 300;     // 1024 x 64
constexpr long OFF_SJ0  = OFF_SI0  + 1024L * 64;
constexpr long OFF_F1   = OFF_SJ0  + 1024L * 64;      // 1024 x 300
constexpr long OFF_H1   = OFF_F1   + 1024L * 300;
constexpr long OFF_SI1  = OFF_H1   + 1024L * 300;
constexpr long OFF_SJ1  = OFF_SI1  + 1024L * 64;
constexpr long OFF_ZP0  = OFF_SJ1  + 1024L * 64;      // 2 x 256 partial sums
constexpr long OFF_ZP1  = OFF_ZP0  + 512;
constexpr long OFF_P0   = OFF_ZP1  + 512;             // 2 x 512 x 512
constexpr long OFF_P1   = OFF_P0   + 2L * 512 * 512;  // total ~9.4 MB

// ---------------------------------------------------------------------------
// Multi-job fp32 GEMM: blockIdx.x -> (job, tile) via prefix offsets.
// Per tile: 32 rows x 64 cols, 256 threads, 2x4 micro-tile, TK=32,
// register-prefetched staging, plain stores (NO atomics, NO split-K).
//   C = (Zp ? 1/sum(Zp[0..255]) : 1) * A@W + bias
// Row/col/K tails fully guarded (zero-fill into LDS; predicated stores).
// ---------------------------------------------------------------------------
struct Jobs {
    const float* A[8]; const float* W[8]; const float* bias[8]; const float* Zp[8];
    float* C[8];
    int K[8]; int lda[8]; int Cc[8]; int R[8];
    int off[8]; int njobs;
};

__global__ __launch_bounds__(256)
void gemm_multi(Jobs jb)
{
    __shared__ __align__(16) float As[32][38];  // [k][m], even stride for b64 reads
    __shared__ __align__(16) float Ws[32][64];  // [k][n]

    const int bid = blockIdx.x;
    int j = jb.njobs - 1;
    while (j > 0 && bid < jb.off[j]) --j;
    const int local = bid - jb.off[j];

    const float* __restrict__ A = jb.A[j];
    const float* __restrict__ W = jb.W[j];
    const float* bias = jb.bias[j];
    const float* Zp   = jb.Zp[j];
    float* __restrict__ C = jb.C[j];
    const int K = jb.K[j], lda = jb.lda[j], Cc = jb.Cc[j], R = jb.R[j];

    const int tx   = (Cc + 63) >> 6;
    const int row0 = (local / tx) * 32;
    const int col0 = (local % tx) * 64;

    const int t   = threadIdx.x;
    const int ar  = t >> 3;               // 0..31 (A row within tile)
    const int ak  = (t & 7) * 4;          // 0..28 (A k sub-offset)
    const int arow = min(row0 + ar, R - 1);
    const int wk  = t >> 4;               // 0..15 (W k rows wk, wk+16)
    const int wc  = (t & 15) * 4;         // 0..60
    const int tm0 = (t >> 4) * 2;
    const int tn0 = (t & 15) * 4;

    auto loadA = [&](int k0) -> float4 {
        const int k = k0 + ak;
        if (k + 3 < K) return *(const float4*)(A + (long)arow * lda + k);
        float tv[4];
        #pragma unroll
        for (int u = 0; u < 4; ++u)
            tv[u] = (k + u < K) ? A[(long)arow * lda + k + u] : 0.0f;
        return make_float4(tv[0], tv[1], tv[2], tv[3]);
    };
    auto loadW = [&](int k0, int s) -> float4 {
        const int gk = k0 + wk + 16 * s;
        if (gk < K) {
            const int c = col0 + wc;
            if (c + 3 < Cc) return *(const float4*)(W + (long)gk * Cc + c);
            float tv[4];
            #pragma unroll
            for (int u = 0; u < 4; ++u)
                tv[u] = (c + u < Cc) ? W[(long)gk * Cc + c + u] : 0.0f;
            return make_float4(tv[0], tv[1], tv[2], tv[3]);
        }
        return make_float4(0.f, 0.f, 0.f, 0.f);
    };

    float acc[2][4] = {};
    float4 av  = loadA(0);
    float4 wv0 = loadW(0, 0);
    float4 wv1 = loadW(0, 1);

    for (int k0 = 0; k0 < K; k0 += 32) {
        As[ak + 0][ar] = av.x;
        As[ak + 1][ar] = av.y;
        As[ak + 2][ar] = av.z;
        As[ak + 3][ar] = av.w;
        *(float4*)&Ws[wk][wc]      = wv0;
        *(float4*)&Ws[wk + 16][wc] = wv1;
        __syncthreads();

        if (k0 + 32 < K) {                 // prefetch next slab behind compute
            av  = loadA(k0 + 32);
            wv0 = loadW(k0 + 32, 0);
            wv1 = loadW(k0 + 32, 1);
        }

        #pragma unroll
        for (int k = 0; k < 32; ++k) {     // zero-padded tails: always full 32
            const float a0 = As[k][tm0];
            const float a1 = As[k][tm0 + 1];
            const float4 w4 = *(const float4*)&Ws[k][tn0];
            acc[0][0] = fmaf(a0, w4.x, acc[0][0]);
            acc[0][1] = fmaf(a0, w4.y, acc[0][1]);
            acc[0][2] = fmaf(a0, w4.z, acc[0][2]);
            acc[0][3] = fmaf(a0, w4.w, acc[0][3]);
            acc[1][0] = fmaf(a1, w4.x, acc[1][0]);
            acc[1][1] = fmaf(a1, w4.y, acc[1][1]);
            acc[1][2] = fmaf(a1, w4.z, acc[1][2]);
            acc[1][3] = fmaf(a1, w4.w, acc[1][3]);
        }
        __syncthreads();
    }

    float scale = 1.0f;
    if (Zp != nullptr) {                   // softmax denom from per-tile partials
        float s0 = 0.f, s1 = 0.f, s2 = 0.f, s3 = 0.f;
        for (int u = 0; u < 256; u += 4) {
            s0 += Zp[u]; s1 += Zp[u + 1]; s2 += Zp[u + 2]; s3 += Zp[u + 3];
        }
        scale = 1.0f / ((s0 + s1) + (s2 + s3));
    }
    const int cbase = col0 + tn0;
    float bv[4] = {0.f, 0.f, 0.f, 0.f};
    if (bias != nullptr) {
        #pragma unroll
        for (int u = 0; u < 4; ++u)
            if (cbase + u < Cc) bv[u] = bias[cbase + u];
    }
    #pragma unroll
    for (int i = 0; i < 2; ++i) {
        const int r = row0 + tm0 + i;
        if (r < R) {
            if (cbase + 3 < Cc) {
                float4 o;
                o.x = fmaf(acc[i][0], scale, bv[0]);
                o.y = fmaf(acc[i][1], scale, bv[1]);
                o.z = fmaf(acc[i][2], scale, bv[2]);
                o.w = fmaf(acc[i][3], scale, bv[3]);
                *(float4*)(C + (long)r * Cc + cbase) = o;
            } else {
                #pragma unroll
                for (int u = 0; u < 4; ++u)
                    if (cbase + u < Cc)
                        C[(long)r * Cc + cbase + u] = fmaf(acc[i][u], scale, bv[u]);
            }
        }
    }
}

// ---------------------------------------------------------------------------
// Attention numerator (32i x 32j tile per block):
//   e = leaky_relu( sum_h relu(si[i,h]+sj[j,h]) * a2w[h] + a2b )
//   p = adj * exp(e);  Zpart[b*256+tile] = sum(p)  (plain store — no atomics)
// Max-subtraction skipped: |e| = O(10), fp32 exp exact-safe; softmax over the
// flat N*N per batch so sum(Zpart)/batch is the exact denominator.
// ---------------------------------------------------------------------------
__global__ __launch_bounds__(256)
void attn_p_kernel(const float* __restrict__ si, const float* __restrict__ sj,
                   const float* __restrict__ adj, const float* __restrict__ a2w,
                   const float* __restrict__ a2b, float* __restrict__ p,
                   float* __restrict__ Zpart)
{
    __shared__ __align__(16) float Si[32][68];
    __shared__ __align__(16) float Sj[32][68];

    const int b  = blockIdx.z;
    const int i0 = blockIdx.y * 32;
    const int j0 = blockIdx.x * 32;
    const int t  = threadIdx.x;

    {   // stage 32x64 tiles of si and sj
        const int r  = t >> 3;
        const int hc = (t & 7) * 8;
        const float* gi = si + ((long)(b * N_ + i0 + r)) * H_ + hc;
        const float* gj = sj + ((long)(b * N_ + j0 + r)) * H_ + hc;
        *(float4*)&Si[r][hc]     = *(const float4*)(gi);
        *(float4*)&Si[r][hc + 4] = *(const float4*)(gi + 4);
        *(float4*)&Sj[r][hc]     = *(const float4*)(gj);
        *(float4*)&Sj[r][hc + 4] = *(const float4*)(gj + 4);
    }
    __syncthreads();

    const int i  = t >> 3;
    const int jl = t & 7;

    float e[4] = {0.f, 0.f, 0.f, 0.f};
    #pragma unroll
    for (int h0 = 0; h0 < H_; h0 += 4) {
        const float4 a4 = *(const float4*)&Si[i][h0];
        const float w0v = a2w[h0 + 0];
        const float w1v = a2w[h0 + 1];
        const float w2v = a2w[h0 + 2];
        const float w3v = a2w[h0 + 3];
        #pragma unroll
        for (int u = 0; u < 4; ++u) {
            const float4 b4 = *(const float4*)&Sj[jl + 8 * u][h0];
            e[u] = fmaf(fmaxf(a4.x + b4.x, 0.f), w0v, e[u]);
            e[u] = fmaf(fmaxf(a4.y + b4.y, 0.f), w1v, e[u]);
            e[u] = fmaf(fmaxf(a4.z + b4.z, 0.f), w2v, e[u]);
            e[u] = fmaf(fmaxf(a4.w + b4.w, 0.f), w3v, e[u]);
        }
    }

    const float a2bv = a2b[0];
    const long rowbase = ((long)(b * N_ + i0 + i)) * N_ + j0 + jl;
    float lsum = 0.f;
    #pragma unroll
    for (int u = 0; u < 4; ++u) {
        float ev = e[u] + a2bv;
        ev = (ev >= 0.f) ? ev : SLOPE_ * ev;
        const float m  = adj[rowbase + 8 * u];
        const float pv = m * __expf(ev);
        p[rowbase + 8 * u] = pv;
        lsum += pv;
    }

    #pragma unroll
    for (int off = 32; off > 0; off >>= 1)
        lsum += __shfl_down(lsum, off, 64);
    __shared__ float red[4];
    if ((t & 63) == 0) red[t >> 6] = lsum;
    __syncthreads();
    if (t == 0)
        Zpart[b * 256 + blockIdx.y * 16 + blockIdx.x] =
            red[0] + red[1] + red[2] + red[3];
}

} // namespace

extern "C" void kernel_launch(void* const* d_in, const int* in_sizes, int n_in,
                              void* d_out, int out_size, void* d_ws, size_t ws_size,
                              hipStream_t stream)
{
    const float* feature = (const float*)d_in[0];
    const float* adj     = (const float*)d_in[1];
    const float* w0      = (const float*)d_in[2];
    const float* b0      = (const float*)d_in[3];
    const float* w1      = (const float*)d_in[4];
    const float* b1      = (const float*)d_in[5];
    const float* a1w     = (const float*)d_in[6];   // (600, 64) row-major
    const float* a1b     = (const float*)d_in[7];
    const float* a2w     = (const float*)d_in[8];
    const float* a2b     = (const float*)d_in[9];
    float* out = (float*)d_out;
    float* ws  = (float*)d_ws;

    float* cW0Ai = ws + OFF_W0AI;
    float* cW0Aj = ws + OFF_W0AJ;
    float* cW1Ai = ws + OFF_W1AI;
    float* cW1Aj = ws + OFF_W1AJ;
    float* bsi0  = ws + OFF_BSI0;
    float* bsj0  = ws + OFF_BSJ0;
    float* bsi1  = ws + OFF_BSI1;
    float* bsj1  = ws + OFF_BSJ1;
    float* h0    = ws + OFF_H0;
    float* si0   = ws + OFF_SI0;
    float* sj0   = ws + OFF_SJ0;
    float* f1    = ws + OFF_F1;
    float* h1    = ws + OFF_H1;
    float* si1   = ws + OFF_SI1;
    float* sj1   = ws + OFF_SJ1;
    float* Zp0   = ws + OFF_ZP0;
    float* Zp1   = ws + OFF_ZP1;
    float* p0    = ws + OFF_P0;
    float* p1    = ws + OFF_P1;

    const float* Ai = a1w;                    // top half (300 x 64)
    const float* Aj = a1w + (long)M_ * H_;    // bottom half

    auto set_job = [](Jobs& jb, int j, const float* A, const float* W,
                      const float* bias, const float* Zp, float* C,
                      int K, int lda, int Cc, int R, int& tiles) {
        jb.A[j] = A; jb.W[j] = W; jb.bias[j] = bias; jb.Zp[j] = Zp; jb.C[j] = C;
        jb.K[j] = K; jb.lda[j] = lda; jb.Cc[j] = Cc; jb.R[j] = R;
        jb.off[j] = tiles;
        tiles += ((R + 31) / 32) * ((Cc + 63) / 64);
    };

    // ---- D1: fused attention-projection weights + bias combos ----
    // si = h@Ai = x@(w@Ai) + (b@Ai);  sj = x@(w@Aj) + (b@Aj + a1b)
    {
        Jobs jb; int tiles = 0;
        set_job(jb, 0, w0, Ai, nullptr, nullptr, cW0Ai, M_, M_, H_, IN_, tiles);
        set_job(jb, 1, w0, Aj, nullptr, nullptr, cW0Aj, M_, M_, H_, IN_, tiles);
        set_job(jb, 2, w1, Ai, nullptr, nullptr, cW1Ai, M_, M_, H_, M_,  tiles);
        set_job(jb, 3, w1, Aj, nullptr, nullptr, cW1Aj, M_, M_, H_, M_,  tiles);
        set_job(jb, 4, b0, Ai, nullptr, nullptr, bsi0,  M_, M_, H_, 1,   tiles);
        set_job(jb, 5, b0, Aj, a1b,     nullptr, bsj0,  M_, M_, H_, 1,   tiles);
        set_job(jb, 6, b1, Ai, nullptr, nullptr, bsi1,  M_, M_, H_, 1,   tiles);
        set_job(jb, 7, b1, Aj, a1b,     nullptr, bsj1,  M_, M_, H_, 1,   tiles);
        jb.njobs = 8;
        gemm_multi<<<dim3(tiles), dim3(256), 0, stream>>>(jb);  // 56 blocks
    }

    // ---- D2: layer-0 node projection + attention features (independent) ----
    {
        Jobs jb; int tiles = 0;
        set_job(jb, 0, feature, w0,    b0,   nullptr, h0,  IN_, IN_, M_, 1024, tiles);
        set_job(jb, 1, feature, cW0Ai, bsi0, nullptr, si0, IN_, IN_, H_, 1024, tiles);
        set_job(jb, 2, feature, cW0Aj, bsj0, nullptr, sj0, IN_, IN_, H_, 1024, tiles);
        jb.njobs = 3;
        gemm_multi<<<dim3(tiles), dim3(256), 0, stream>>>(jb);  // 224 blocks
    }

    // ---- D3: p0 + Zpart0 ----
    attn_p_kernel<<<dim3(16, 16, B_), dim3(256), 0, stream>>>(
        si0, sj0, adj, a2w, a2b, p0, Zp0);

    // ---- D4: f1 = (1/Z0[b]) * p0 @ h0 ----
    {
        Jobs jb; int tiles = 0;
        set_job(jb, 0, p0,               h0,            nullptr, Zp0,       f1,
                N_, N_, M_, N_, tiles);
        set_job(jb, 1, p0 + (long)N_*N_, h0 + (long)N_*M_, nullptr, Zp0 + 256,
                f1 + (long)N_*M_, N_, N_, M_, N_, tiles);
        jb.njobs = 2;
        gemm_multi<<<dim3(tiles), dim3(256), 0, stream>>>(jb);  // 160 blocks
    }

    // ---- D5: layer-1 projections (independent given f1) ----
    {
        Jobs jb; int tiles = 0;
        set_job(jb, 0, f1, w1,    b1,   nullptr, h1,  M_, M_, M_, 1024, tiles);
        set_job(jb, 1, f1, cW1Ai, bsi1, nullptr, si1, M_, M_, H_, 1024, tiles);
        set_job(jb, 2, f1, cW1Aj, bsj1, nullptr, sj1, M_, M_, H_, 1024, tiles);
        jb.njobs = 3;
        gemm_multi<<<dim3(tiles), dim3(256), 0, stream>>>(jb);  // 224 blocks
    }

    // ---- D6: p1 + Zpart1 ----
    attn_p_kernel<<<dim3(16, 16, B_), dim3(256), 0, stream>>>(
        si1, sj1, adj, a2w, a2b, p1, Zp1);

    // ---- D7: out = (1/Z1[b]) * p1 @ h1 ----
    {
        Jobs jb; int tiles = 0;
        set_job(jb, 0, p1,               h1,            nullptr, Zp1,       out,
                N_, N_, M_, N_, tiles);
        set_job(jb, 1, p1 + (long)N_*N_, h1 + (long)N_*M_, nullptr, Zp1 + 256,
                out + (long)N_*M_, N_, N_, M_, N_, tiles);
        jb.njobs = 2;
        gemm_multi<<<dim3(tiles), dim3(256), 0, stream>>>(jb);  // 160 blocks
    }
}